// Round 2
// baseline (1073.760 us; speedup 1.0000x reference)
//
#include <hip/hip_runtime.h>
#include <hip/hip_bf16.h>
#include <stdint.h>

#define NUM_CLASS 100000
#define EMB 512
#define BATCH 1024
#define S_SCALE 64.0f
#define T_HARD 1.2f            // T + 1
#define COS_M   0.8775825618903728f
#define SIN_M   0.479425538604203f
#define THETA_C (-0.8775825618903728f)   // cos(pi - M)
#define SINMM   0.2397127693021015f      // sin(pi - M) * M
#define COS_M1  0.9800665778412416f
#define SIN_M1  0.19866933079506122f
#define SINMM1  (-0.039733866159012244f) // sin(-M1) * M1

#define NCOL_TILES 782
#define GRID_X (8 * NCOL_TILES)          // 6256 blocks

typedef __attribute__((ext_vector_type(8))) short bf16x8;
typedef __attribute__((ext_vector_type(4))) float floatx4;

__device__ __forceinline__ unsigned short f2bf(float f) {
    union { float f; unsigned u; } v; v.f = f;
    unsigned r = v.u + 0x7fffu + ((v.u >> 16) & 1u);
    return (unsigned short)(r >> 16);
}
__device__ __forceinline__ float blo(unsigned u) {
    union { unsigned v; float f; } c; c.v = u << 16; return c.f;
}
__device__ __forceinline__ float bhi(unsigned u) {
    union { unsigned v; float f; } c; c.v = u & 0xffff0000u; return c.f;
}
__device__ __forceinline__ void load16(const void* g, void* l) {
    __builtin_amdgcn_global_load_lds(
        (const __attribute__((address_space(1))) void*)g,
        (__attribute__((address_space(3))) void*)l, 16, 0, 0);
}

// ---- Kernel 1: normalize embeddings -> bf16 ----
__global__ void k_embed(const float* __restrict__ emb, unsigned short* __restrict__ ne) {
    int row = blockIdx.x;            // 1024
    int t = threadIdx.x;             // 256, 2 floats each
    float2 v = ((const float2*)(emb + row * EMB))[t];
    float ss = v.x * v.x + v.y * v.y;
    __shared__ float red[4];
    for (int off = 32; off; off >>= 1) ss += __shfl_down(ss, off);
    if ((t & 63) == 0) red[t >> 6] = ss;
    __syncthreads();
    float inv = rsqrtf(red[0] + red[1] + red[2] + red[3]);
    unsigned b0 = f2bf(v.x * inv), b1 = f2bf(v.y * inv);
    ((unsigned*)(ne + row * EMB))[t] = b0 | (b1 << 16);
}

// ---- Kernel 2: target logits from RAW fp32 weights (one wave per row) ----
__global__ void k_tl(const unsigned short* __restrict__ ne, const float* __restrict__ w,
                     const int* __restrict__ labels, float* __restrict__ ftl, float* __restrict__ ftl1) {
    int b = blockIdx.x * 4 + (threadIdx.x >> 6);
    int L = threadIdx.x & 63;
    int lab = labels[b];
    uint4 ua = *(const uint4*)(ne + (size_t)b * EMB + L * 8);
    const float4* wp = (const float4*)(w + (size_t)lab * EMB + L * 8);
    float4 w0 = wp[0], w1 = wp[1];
    float ss = w0.x*w0.x + w0.y*w0.y + w0.z*w0.z + w0.w*w0.w
             + w1.x*w1.x + w1.y*w1.y + w1.z*w1.z + w1.w*w1.w;
    float s = blo(ua.x)*w0.x + bhi(ua.x)*w0.y + blo(ua.y)*w0.z + bhi(ua.y)*w0.w
            + blo(ua.z)*w1.x + bhi(ua.z)*w1.y + blo(ua.w)*w1.z + bhi(ua.w)*w1.w;
    for (int off = 32; off; off >>= 1) {
        s  += __shfl_down(s, off);
        ss += __shfl_down(ss, off);
    }
    if (L == 0) {
        float tl = s * rsqrtf(ss);
        tl = fminf(1.0f, fmaxf(-1.0f, tl));
        float st = sqrtf(fmaxf(0.0f, 1.0f - tl * tl));
        float cos_tm  = tl * COS_M  - st * SIN_M;
        float cos_tm1 = tl * COS_M1 - st * SIN_M1;
        float f  = (tl > THETA_C)  ? cos_tm  : (tl - SINMM);
        float f1 = (tl <= COS_M1)  ? cos_tm1 : (tl + SINMM1);
        ftl[b] = f;
        ftl1[b] = f1;
    }
}

// ---- Kernel 3: fused GEMM. A bf16 + B raw fp32, BOTH staged via global_load_lds
// (deep VMEM queue, round-0 proven 2-barrier schedule). fp32->bf16 convert + |w|^2
// accumulate on the LDS->reg fragment path. XOR-swizzled LDS (linear load_lds dest,
// inverse-swizzled global SOURCE, swizzled read) kills the fp32 16-way bank conflict.
__global__ __launch_bounds__(256, 3)
void k_gemm(const unsigned short* __restrict__ A,   // ne [1024][512] bf16
            const float* __restrict__ W,            // raw weight [100000][512] fp32
            const float* __restrict__ ftl, const float* __restrict__ ftl1,
            const int* __restrict__ labels,
            float* __restrict__ out, unsigned* __restrict__ cnt) {
    __shared__ unsigned short ldsA[128 * 32];       // 8 KB, bf16 [128 rows][32 k]
    __shared__ float ldsB32[128 * 32];              // 16 KB, fp32 [128 cols][32 k]
    __shared__ float sF[128], sF1[128], sInvW[128];
    __shared__ int sLab[128];
    __shared__ unsigned sCnt[8];

    const int tid = threadIdx.x;
    // bijective XCD swizzle: all 8 row-tiles of a col-tile on one XCD
    const int flat = blockIdx.x;
    const int p = (flat & 7) * NCOL_TILES + (flat >> 3);
    const int rowBase = (p & 7) * 128;      // 8 row tiles
    const int colBase = (p >> 3) * 128;     // 782 col tiles

    if (tid < 128) {
        sF[tid]  = ftl[rowBase + tid];
        sF1[tid] = ftl1[rowBase + tid];
        sLab[tid] = labels[rowBase + tid];
    }

    const int wave = tid >> 6;
    const int lane = tid & 63;
    const int wm = wave >> 1, wn = wave & 1;

    // ---- A staging (swizzled source): dest granule g=tid (16B), row=tid>>2,
    // k8 = (tid&3) ^ (row&3). Reader XORs the same way.
    {
    }
    const int aRow = tid >> 2;
    const int aK8 = (tid & 3) ^ (aRow & 3);
    const unsigned short* gA = A + (size_t)(rowBase + aRow) * EMB + aK8 * 8;

    // ---- B staging (swizzled source): dest granule g = c*256+tid (float4 units),
    // row = g>>3, k4 = (g&7) ^ (row&7). Coalescing: consecutive tid -> consecutive g
    // -> same row, k4 XOR pattern stays within the row's 8 float4s (128B window).
    const float* gW[4];
    #pragma unroll
    for (int c = 0; c < 4; c++) {
        int g = c * 256 + tid;
        int row = g >> 3;
        int k4 = (g & 7) ^ (row & 7);
        int wr = colBase + row;
        if (wr >= NUM_CLASS) wr = NUM_CLASS - 1;   // clamp OOB tail rows (discarded)
        gW[c] = W + (size_t)wr * EMB + k4 * 4;
    }

    floatx4 acc[4][4] = {};
    float ssq[4] = {0.f, 0.f, 0.f, 0.f};

    for (int kk = 0; kk < EMB; kk += 32) {
        load16(gA + kk, &ldsA[tid * 8]);
        load16(gA + kk + 64 * EMB, &ldsA[2048 + tid * 8]);
        #pragma unroll
        for (int c = 0; c < 4; c++) load16(gW[c] + kk, &ldsB32[(c * 256 + tid) * 4]);
        __syncthreads();

        bf16x8 af[4], bf[4];
        #pragma unroll
        for (int mi = 0; mi < 4; mi++) {
            const int r = wm * 64 + mi * 16 + (lane & 15);
            const int ks = lane >> 4;
            af[mi] = *(const bf16x8*)&ldsA[r * 32 + ((ks ^ (r & 3)) * 8)];
        }
        #pragma unroll
        for (int ni = 0; ni < 4; ni++) {
            const int r = wn * 64 + ni * 16 + (lane & 15);
            const int k4a = (lane >> 4) * 2;
            float4 q0 = *(const float4*)&ldsB32[r * 32 + ((k4a ^ (r & 7)) * 4)];
            float4 q1 = *(const float4*)&ldsB32[r * 32 + (((k4a + 1) ^ (r & 7)) * 4)];
            ssq[ni] += q0.x*q0.x + q0.y*q0.y + q0.z*q0.z + q0.w*q0.w
                     + q1.x*q1.x + q1.y*q1.y + q1.z*q1.z + q1.w*q1.w;
            union { __hip_bfloat162 h[4]; bf16x8 v; } pk;
            pk.h[0] = __float22bfloat162_rn(make_float2(q0.x, q0.y));
            pk.h[1] = __float22bfloat162_rn(make_float2(q0.z, q0.w));
            pk.h[2] = __float22bfloat162_rn(make_float2(q1.x, q1.y));
            pk.h[3] = __float22bfloat162_rn(make_float2(q1.z, q1.w));
            bf[ni] = pk.v;
        }
        // swapped operands: lane&15 = batch row, (lane>>4)*4 + r = class col
        #pragma unroll
        for (int mi = 0; mi < 4; mi++)
            #pragma unroll
            for (int ni = 0; ni < 4; ni++)
                acc[mi][ni] = __builtin_amdgcn_mfma_f32_16x16x32_bf16(bf[ni], af[mi], acc[mi][ni], 0, 0, 0);
        __syncthreads();
    }

    // finalize 1/|w| per column: lane holds ssq for col wn*64+ni*16+(lane&15) over
    // its k-slice; reduce across the 4 k-slice lane groups.
    #pragma unroll
    for (int ni = 0; ni < 4; ni++) {
        float ss = ssq[ni];
        ss += __shfl_xor(ss, 16);
        ss += __shfl_xor(ss, 32);
        if (wm == 0 && lane < 16) sInvW[wn * 64 + ni * 16 + lane] = rsqrtf(ss);
    }
    __syncthreads();

    // epilogue: normalize, clip, masks, counts, label override, scale, nt store
    unsigned cH = 0, cN = 0;
    #pragma unroll
    for (int mi = 0; mi < 4; mi++) {
        const int row = wm * 64 + mi * 16 + (lane & 15);
        const float F = sF[row], F1 = sF1[row];
        const int lab = sLab[row];
        float* orow = out + (size_t)(rowBase + row) * NUM_CLASS;
        #pragma unroll
        for (int ni = 0; ni < 4; ni++) {
            const int colL = wn * 64 + ni * 16 + (lane >> 4) * 4;
            const int col = colBase + colL;
            if (col < NUM_CLASS) {     // 100000 % 4 == 0: chunk fully in or out
                floatx4 a = acc[mi][ni];
                const float* iw = &sInvW[colL];
                floatx4 v;
                #pragma unroll
                for (int r = 0; r < 4; r++) {
                    float lg = fminf(1.0f, fmaxf(-1.0f, a[r] * iw[r]));
                    bool h = lg > F, n = lg > F1;
                    cH += h; cN += n;
                    float val = n ? fmaxf(lg, 1e-30f) : (h ? lg * T_HARD : lg);
                    if (col + r == lab) val = F;
                    v[r] = val * S_SCALE;
                }
                __builtin_nontemporal_store(v, (floatx4*)(orow + col));
            }
        }
    }
    for (int off = 32; off; off >>= 1) { cH += __shfl_down(cH, off); cN += __shfl_down(cN, off); }
    if (lane == 0) { sCnt[wave] = cH; sCnt[4 + wave] = cN; }
    __syncthreads();
    if (tid == 0) {
        unsigned h = sCnt[0] + sCnt[1] + sCnt[2] + sCnt[3];
        unsigned n = sCnt[4] + sCnt[5] + sCnt[6] + sCnt[7];
        atomicAdd(&cnt[0], h);
        atomicAdd(&cnt[1], n);
        __threadfence();
        // last block finalizes the scalar outputs (no extra launch)
        if (atomicAdd(&cnt[2], 1u) == (unsigned)(GRID_X - 1)) {
            unsigned hard_cnt = atomicAdd(&cnt[0], 0u);
            unsigned noise_num = atomicAdd(&cnt[1], 0u);
            const unsigned num_all = (unsigned)BATCH * (unsigned)NUM_CLASS; // 102,400,000
            unsigned easy = num_all - hard_cnt;
            float* o = out + (size_t)BATCH * NUM_CLASS;
            o[0] = (float)easy;
            o[1] = (float)noise_num;
            o[2] = (float)(hard_cnt - noise_num);
            o[3] = ((float)easy / (float)num_all) * 0.01f;
        }
    }
}

extern "C" void kernel_launch(void* const* d_in, const int* in_sizes, int n_in,
                              void* d_out, int out_size, void* d_ws, size_t ws_size,
                              hipStream_t stream) {
    const float* emb = (const float*)d_in[0];
    const float* wgt = (const float*)d_in[1];
    const int* labels = (const int*)d_in[2];
    float* out = (float*)d_out;
    char* ws = (char*)d_ws;

    unsigned* cnt = (unsigned*)ws;                           // 64 B (incl. ticket)
    float* ftl  = (float*)(ws + 64);                         // 4 KB
    float* ftl1 = (float*)(ws + 8192);                       // 4 KB
    unsigned short* ne = (unsigned short*)(ws + 16384);      // 1 MB

    hipMemsetAsync(cnt, 0, 64, stream);
    k_embed<<<BATCH, 256, 0, stream>>>(emb, ne);
    k_tl<<<BATCH / 4, 256, 0, stream>>>(ne, wgt, labels, ftl, ftl1);
    k_gemm<<<GRID_X, 256, 0, stream>>>(ne, wgt, ftl, ftl1, labels, out, cnt);
}

// Round 3
// 788.522 us; speedup vs baseline: 1.3617x; 1.3617x over previous
//
#include <hip/hip_runtime.h>
#include <hip/hip_bf16.h>
#include <stdint.h>

#define NUM_CLASS 100000
#define EMB 512
#define BATCH 1024
#define S_SCALE 64.0f
#define T_HARD 1.2f            // T + 1
#define COS_M   0.8775825618903728f
#define SIN_M   0.479425538604203f
#define THETA_C (-0.8775825618903728f)   // cos(pi - M)
#define SINMM   0.2397127693021015f      // sin(pi - M) * M
#define COS_M1  0.9800665778412416f
#define SIN_M1  0.19866933079506122f
#define SINMM1  (-0.039733866159012244f) // sin(-M1) * M1

#define NCOL_TILES 782
#define GRID_X (8 * NCOL_TILES)          // 6256 blocks

typedef __attribute__((ext_vector_type(8))) short bf16x8;
typedef __attribute__((ext_vector_type(4))) float floatx4;

__device__ __forceinline__ unsigned short f2bf(float f) {
    union { float f; unsigned u; } v; v.f = f;
    unsigned r = v.u + 0x7fffu + ((v.u >> 16) & 1u);
    return (unsigned short)(r >> 16);
}
__device__ __forceinline__ float blo(unsigned u) {
    union { unsigned v; float f; } c; c.v = u << 16; return c.f;
}
__device__ __forceinline__ float bhi(unsigned u) {
    union { unsigned v; float f; } c; c.v = u & 0xffff0000u; return c.f;
}
__device__ __forceinline__ void load16(const void* g, void* l) {
    __builtin_amdgcn_global_load_lds(
        (const __attribute__((address_space(1))) void*)g,
        (__attribute__((address_space(3))) void*)l, 16, 0, 0);
}

// ---- Kernel 1: normalize embeddings -> bf16 ----
__global__ void k_embed(const float* __restrict__ emb, unsigned short* __restrict__ ne) {
    int row = blockIdx.x;            // 1024
    int t = threadIdx.x;             // 256, 2 floats each
    float2 v = ((const float2*)(emb + row * EMB))[t];
    float ss = v.x * v.x + v.y * v.y;
    __shared__ float red[4];
    for (int off = 32; off; off >>= 1) ss += __shfl_down(ss, off);
    if ((t & 63) == 0) red[t >> 6] = ss;
    __syncthreads();
    float inv = rsqrtf(red[0] + red[1] + red[2] + red[3]);
    unsigned b0 = f2bf(v.x * inv), b1 = f2bf(v.y * inv);
    ((unsigned*)(ne + row * EMB))[t] = b0 | (b1 << 16);
}

// ---- Kernel 2: target logits from RAW fp32 weights (one wave per row) ----
__global__ void k_tl(const unsigned short* __restrict__ ne, const float* __restrict__ w,
                     const int* __restrict__ labels, float* __restrict__ ftl, float* __restrict__ ftl1) {
    int b = blockIdx.x * 4 + (threadIdx.x >> 6);
    int L = threadIdx.x & 63;
    int lab = labels[b];
    uint4 ua = *(const uint4*)(ne + (size_t)b * EMB + L * 8);
    const float4* wp = (const float4*)(w + (size_t)lab * EMB + L * 8);
    float4 w0 = wp[0], w1 = wp[1];
    float ss = w0.x*w0.x + w0.y*w0.y + w0.z*w0.z + w0.w*w0.w
             + w1.x*w1.x + w1.y*w1.y + w1.z*w1.z + w1.w*w1.w;
    float s = blo(ua.x)*w0.x + bhi(ua.x)*w0.y + blo(ua.y)*w0.z + bhi(ua.y)*w0.w
            + blo(ua.z)*w1.x + bhi(ua.z)*w1.y + blo(ua.w)*w1.z + bhi(ua.w)*w1.w;
    for (int off = 32; off; off >>= 1) {
        s  += __shfl_down(s, off);
        ss += __shfl_down(ss, off);
    }
    if (L == 0) {
        float tl = s * rsqrtf(ss);
        tl = fminf(1.0f, fmaxf(-1.0f, tl));
        float st = sqrtf(fmaxf(0.0f, 1.0f - tl * tl));
        float cos_tm  = tl * COS_M  - st * SIN_M;
        float cos_tm1 = tl * COS_M1 - st * SIN_M1;
        float f  = (tl > THETA_C)  ? cos_tm  : (tl - SINMM);
        float f1 = (tl <= COS_M1)  ? cos_tm1 : (tl + SINMM1);
        ftl[b] = f;
        ftl1[b] = f1;
    }
}

// ---- Kernel 3: fused GEMM. A bf16 + B raw fp32, BOTH staged via global_load_lds.
// fp32->bf16 convert + |w|^2 accumulate on the LDS->reg fragment path.
// NO device-scope fence in this kernel (threadfence's buffer_inv wiped L2 every
// ~1us in rounds 1-2 -> all pipes idle). Finalize is a separate tiny launch.
__global__ __launch_bounds__(256, 3)
void k_gemm(const unsigned short* __restrict__ A,   // ne [1024][512] bf16
            const float* __restrict__ W,            // raw weight [100000][512] fp32
            const float* __restrict__ ftl, const float* __restrict__ ftl1,
            const int* __restrict__ labels,
            float* __restrict__ out, unsigned* __restrict__ cnt) {
    __shared__ unsigned short ldsA[128 * 32];       // 8 KB, bf16 [128 rows][32 k]
    __shared__ float ldsB32[128 * 32];              // 16 KB, fp32 [128 cols][32 k]
    __shared__ float sF[128], sF1[128], sInvW[128];
    __shared__ int sLab[128];
    __shared__ unsigned sCnt[8];

    const int tid = threadIdx.x;
    // bijective XCD swizzle: all 8 row-tiles of a col-tile on one XCD
    const int flat = blockIdx.x;
    const int p = (flat & 7) * NCOL_TILES + (flat >> 3);
    const int rowBase = (p & 7) * 128;      // 8 row tiles
    const int colBase = (p >> 3) * 128;     // 782 col tiles

    if (tid < 128) {
        sF[tid]  = ftl[rowBase + tid];
        sF1[tid] = ftl1[rowBase + tid];
        sLab[tid] = labels[rowBase + tid];
    }

    const int wave = tid >> 6;
    const int lane = tid & 63;
    const int wm = wave >> 1, wn = wave & 1;

    // A staging (swizzled source): dest granule g=tid (16B), row=tid>>2,
    // k8 = (tid&3) ^ (row&3). Reader XORs the same way.
    const int aRow = tid >> 2;
    const int aK8 = (tid & 3) ^ (aRow & 3);
    const unsigned short* gA = A + (size_t)(rowBase + aRow) * EMB + aK8 * 8;

    // B staging (swizzled source): dest granule g = c*256+tid (float4 units),
    // row = g>>3, k4 = (g&7) ^ (row&7).
    const float* gW[4];
    #pragma unroll
    for (int c = 0; c < 4; c++) {
        int g = c * 256 + tid;
        int row = g >> 3;
        int k4 = (g & 7) ^ (row & 7);
        int wr = colBase + row;
        if (wr >= NUM_CLASS) wr = NUM_CLASS - 1;   // clamp OOB tail rows (discarded)
        gW[c] = W + (size_t)wr * EMB + k4 * 4;
    }

    floatx4 acc[4][4] = {};
    float ssq[4] = {0.f, 0.f, 0.f, 0.f};

    for (int kk = 0; kk < EMB; kk += 32) {
        load16(gA + kk, &ldsA[tid * 8]);
        load16(gA + kk + 64 * EMB, &ldsA[2048 + tid * 8]);
        #pragma unroll
        for (int c = 0; c < 4; c++) load16(gW[c] + kk, &ldsB32[(c * 256 + tid) * 4]);
        __syncthreads();

        bf16x8 af[4], bf[4];
        #pragma unroll
        for (int mi = 0; mi < 4; mi++) {
            const int r = wm * 64 + mi * 16 + (lane & 15);
            const int ks = lane >> 4;
            af[mi] = *(const bf16x8*)&ldsA[r * 32 + ((ks ^ (r & 3)) * 8)];
        }
        #pragma unroll
        for (int ni = 0; ni < 4; ni++) {
            const int r = wn * 64 + ni * 16 + (lane & 15);
            const int k4a = (lane >> 4) * 2;
            float4 q0 = *(const float4*)&ldsB32[r * 32 + ((k4a ^ (r & 7)) * 4)];
            float4 q1 = *(const float4*)&ldsB32[r * 32 + (((k4a + 1) ^ (r & 7)) * 4)];
            ssq[ni] += q0.x*q0.x + q0.y*q0.y + q0.z*q0.z + q0.w*q0.w
                     + q1.x*q1.x + q1.y*q1.y + q1.z*q1.z + q1.w*q1.w;
            union { __hip_bfloat162 h[4]; bf16x8 v; } pk;
            pk.h[0] = __float22bfloat162_rn(make_float2(q0.x, q0.y));
            pk.h[1] = __float22bfloat162_rn(make_float2(q0.z, q0.w));
            pk.h[2] = __float22bfloat162_rn(make_float2(q1.x, q1.y));
            pk.h[3] = __float22bfloat162_rn(make_float2(q1.z, q1.w));
            bf[ni] = pk.v;
        }
        // swapped operands: lane&15 = batch row, (lane>>4)*4 + r = class col
        #pragma unroll
        for (int mi = 0; mi < 4; mi++)
            #pragma unroll
            for (int ni = 0; ni < 4; ni++)
                acc[mi][ni] = __builtin_amdgcn_mfma_f32_16x16x32_bf16(bf[ni], af[mi], acc[mi][ni], 0, 0, 0);
        __syncthreads();
    }

    // finalize 1/|w| per column: reduce ssq across the 4 k-slice lane groups
    #pragma unroll
    for (int ni = 0; ni < 4; ni++) {
        float ss = ssq[ni];
        ss += __shfl_xor(ss, 16);
        ss += __shfl_xor(ss, 32);
        if (wm == 0 && lane < 16) sInvW[wn * 64 + ni * 16 + lane] = rsqrtf(ss);
    }
    __syncthreads();

    // epilogue: normalize, clip, masks, counts, label override, scale, nt store
    unsigned cH = 0, cN = 0;
    #pragma unroll
    for (int mi = 0; mi < 4; mi++) {
        const int row = wm * 64 + mi * 16 + (lane & 15);
        const float F = sF[row], F1 = sF1[row];
        const int lab = sLab[row];
        float* orow = out + (size_t)(rowBase + row) * NUM_CLASS;
        #pragma unroll
        for (int ni = 0; ni < 4; ni++) {
            const int colL = wn * 64 + ni * 16 + (lane >> 4) * 4;
            const int col = colBase + colL;
            if (col < NUM_CLASS) {     // 100000 % 4 == 0: chunk fully in or out
                floatx4 a = acc[mi][ni];
                const float* iw = &sInvW[colL];
                floatx4 v;
                #pragma unroll
                for (int r = 0; r < 4; r++) {
                    float lg = fminf(1.0f, fmaxf(-1.0f, a[r] * iw[r]));
                    bool h = lg > F, n = lg > F1;
                    cH += h; cN += n;
                    float val = n ? fmaxf(lg, 1e-30f) : (h ? lg * T_HARD : lg);
                    if (col + r == lab) val = F;
                    v[r] = val * S_SCALE;
                }
                __builtin_nontemporal_store(v, (floatx4*)(orow + col));
            }
        }
    }
    for (int off = 32; off; off >>= 1) { cH += __shfl_down(cH, off); cN += __shfl_down(cN, off); }
    if (lane == 0) { sCnt[wave] = cH; sCnt[4 + wave] = cN; }
    __syncthreads();
    if (tid == 0) {
        atomicAdd(&cnt[0], sCnt[0] + sCnt[1] + sCnt[2] + sCnt[3]);
        atomicAdd(&cnt[1], sCnt[4] + sCnt[5] + sCnt[6] + sCnt[7]);
    }
}

// ---- Kernel 4: finalize scalar outputs (separate launch: keeps fences out of k_gemm) ----
__global__ void k_final(const unsigned* __restrict__ cnt, float* __restrict__ o) {
    unsigned hard_cnt = cnt[0], noise_num = cnt[1];
    const unsigned num_all = (unsigned)BATCH * (unsigned)NUM_CLASS;   // 102,400,000
    unsigned easy = num_all - hard_cnt;
    unsigned hard_num = hard_cnt - noise_num;
    float phi = ((float)easy / (float)num_all) * 0.01f;
    o[0] = (float)easy;
    o[1] = (float)noise_num;
    o[2] = (float)hard_num;
    o[3] = phi;
}

extern "C" void kernel_launch(void* const* d_in, const int* in_sizes, int n_in,
                              void* d_out, int out_size, void* d_ws, size_t ws_size,
                              hipStream_t stream) {
    const float* emb = (const float*)d_in[0];
    const float* wgt = (const float*)d_in[1];
    const int* labels = (const int*)d_in[2];
    float* out = (float*)d_out;
    char* ws = (char*)d_ws;

    unsigned* cnt = (unsigned*)ws;                           // 64 B
    float* ftl  = (float*)(ws + 64);                         // 4 KB
    float* ftl1 = (float*)(ws + 8192);                       // 4 KB
    unsigned short* ne = (unsigned short*)(ws + 16384);      // 1 MB

    hipMemsetAsync(cnt, 0, 64, stream);
    k_embed<<<BATCH, 256, 0, stream>>>(emb, ne);
    k_tl<<<BATCH / 4, 256, 0, stream>>>(ne, wgt, labels, ftl, ftl1);
    k_gemm<<<GRID_X, 256, 0, stream>>>(ne, wgt, ftl, ftl1, labels, out, cnt);
    k_final<<<1, 1, 0, stream>>>(cnt, out + (size_t)BATCH * NUM_CLASS);
}

// Round 4
// 763.690 us; speedup vs baseline: 1.4060x; 1.0325x over previous
//
#include <hip/hip_runtime.h>
#include <hip/hip_bf16.h>
#include <stdint.h>

#define NUM_CLASS 100000
#define NUM_CLASS_PAD 100096
#define EMB 512
#define BATCH 1024
#define S_SCALE 64.0f
#define T_HARD 1.2f            // T + 1
#define COS_M   0.8775825618903728f
#define SIN_M   0.479425538604203f
#define THETA_C (-0.8775825618903728f)   // cos(pi - M)
#define SINMM   0.2397127693021015f      // sin(pi - M) * M
#define COS_M1  0.9800665778412416f
#define SIN_M1  0.19866933079506122f
#define SINMM1  (-0.039733866159012244f) // sin(-M1) * M1

#define NCOL_TILES 782
#define GRID_X (8 * NCOL_TILES)          // 6256 blocks

typedef __attribute__((ext_vector_type(8))) short bf16x8;
typedef __attribute__((ext_vector_type(4))) float floatx4;

__device__ __forceinline__ unsigned short f2bf(float f) {
    union { float f; unsigned u; } v; v.f = f;
    unsigned r = v.u + 0x7fffu + ((v.u >> 16) & 1u);
    return (unsigned short)(r >> 16);
}
__device__ __forceinline__ float blo(unsigned u) {
    union { unsigned v; float f; } c; c.v = u << 16; return c.f;
}
__device__ __forceinline__ float bhi(unsigned u) {
    union { unsigned v; float f; } c; c.v = u & 0xffff0000u; return c.f;
}
__device__ __forceinline__ void load16(const void* g, void* l) {
    __builtin_amdgcn_global_load_lds(
        (const __attribute__((address_space(1))) void*)g,
        (__attribute__((address_space(3))) void*)l, 16, 0, 0);
}

// ---- Kernel 1: normalize embeddings -> bf16 ----
__global__ void k_embed(const float* __restrict__ emb, unsigned short* __restrict__ ne) {
    int row = blockIdx.x;            // 1024
    int t = threadIdx.x;             // 256, 2 floats each
    float2 v = ((const float2*)(emb + row * EMB))[t];
    float ss = v.x * v.x + v.y * v.y;
    __shared__ float red[4];
    for (int off = 32; off; off >>= 1) ss += __shfl_down(ss, off);
    if ((t & 63) == 0) red[t >> 6] = ss;
    __syncthreads();
    float inv = rsqrtf(red[0] + red[1] + red[2] + red[3]);
    unsigned b0 = f2bf(v.x * inv), b1 = f2bf(v.y * inv);
    ((unsigned*)(ne + row * EMB))[t] = b0 | (b1 << 16);
}

// ---- Kernel 2: normalize weights -> bf16 (one wave per row, padded to 100096) ----
// Plain stores (not nontemporal): nw stays L2/L3-resident for k_gemm to re-read.
__global__ void k_weight(const float* __restrict__ w, unsigned short* __restrict__ nw) {
    int r = blockIdx.x * 4 + (threadIdx.x >> 6);
    int L = threadIdx.x & 63;
    uint4* dst = (uint4*)(nw + (size_t)r * EMB + L * 8);
    if (r >= NUM_CLASS) { *dst = make_uint4(0, 0, 0, 0); return; }
    const float4* src = (const float4*)(w + (size_t)r * EMB + L * 8);
    float4 a = src[0], b = src[1];
    float ss = a.x*a.x + a.y*a.y + a.z*a.z + a.w*a.w
             + b.x*b.x + b.y*b.y + b.z*b.z + b.w*b.w;
    for (int off = 32; off; off >>= 1) ss += __shfl_down(ss, off);
    ss = __shfl(ss, 0);
    float inv = rsqrtf(ss);
    uint4 o;
    o.x = (unsigned)f2bf(a.x*inv) | ((unsigned)f2bf(a.y*inv) << 16);
    o.y = (unsigned)f2bf(a.z*inv) | ((unsigned)f2bf(a.w*inv) << 16);
    o.z = (unsigned)f2bf(b.x*inv) | ((unsigned)f2bf(b.y*inv) << 16);
    o.w = (unsigned)f2bf(b.z*inv) | ((unsigned)f2bf(b.w*inv) << 16);
    *dst = o;
}

// ---- Kernel 3: target logits from RAW fp32 weights (one wave per row) ----
// Independent of k_weight (reads raw W) -> can overlap with it on the GPU.
__global__ void k_tl(const unsigned short* __restrict__ ne, const float* __restrict__ w,
                     const int* __restrict__ labels, float* __restrict__ ftl, float* __restrict__ ftl1) {
    int b = blockIdx.x * 4 + (threadIdx.x >> 6);
    int L = threadIdx.x & 63;
    int lab = labels[b];
    uint4 ua = *(const uint4*)(ne + (size_t)b * EMB + L * 8);
    const float4* wp = (const float4*)(w + (size_t)lab * EMB + L * 8);
    float4 w0 = wp[0], w1 = wp[1];
    float ss = w0.x*w0.x + w0.y*w0.y + w0.z*w0.z + w0.w*w0.w
             + w1.x*w1.x + w1.y*w1.y + w1.z*w1.z + w1.w*w1.w;
    float s = blo(ua.x)*w0.x + bhi(ua.x)*w0.y + blo(ua.y)*w0.z + bhi(ua.y)*w0.w
            + blo(ua.z)*w1.x + bhi(ua.z)*w1.y + blo(ua.w)*w1.z + bhi(ua.w)*w1.w;
    for (int off = 32; off; off >>= 1) {
        s  += __shfl_down(s, off);
        ss += __shfl_down(ss, off);
    }
    if (L == 0) {
        float tl = s * rsqrtf(ss);
        tl = fminf(1.0f, fmaxf(-1.0f, tl));
        float st = sqrtf(fmaxf(0.0f, 1.0f - tl * tl));
        float cos_tm  = tl * COS_M  - st * SIN_M;
        float cos_tm1 = tl * COS_M1 - st * SIN_M1;
        float f  = (tl > THETA_C)  ? cos_tm  : (tl - SINMM);
        float f1 = (tl <= COS_M1)  ? cos_tm1 : (tl + SINMM1);
        ftl[b] = f;
        ftl1[b] = f1;
    }
}

// ---- Kernel 4: bf16 MFMA GEMM 128x128 (round-0 proven structure) + XCD swizzle ----
// No fp32 work on the K-loop critical path; no device-scope fence anywhere here.
__global__ __launch_bounds__(256, 4)
void k_gemm(const unsigned short* __restrict__ A,   // ne [1024][512]
            const unsigned short* __restrict__ B,   // nw [100096][512]
            const float* __restrict__ ftl, const float* __restrict__ ftl1,
            const int* __restrict__ labels,
            float* __restrict__ out, unsigned* __restrict__ cnt) {
    __shared__ unsigned short ldsA[128 * 32];
    __shared__ unsigned short ldsB[128 * 32];
    __shared__ float sF[128], sF1[128];
    __shared__ int sLab[128];
    __shared__ unsigned sCnt[8];

    const int tid = threadIdx.x;
    // bijective XCD swizzle: all 8 row-tiles of a col-tile land on one XCD ->
    // B col-panel fetched from HBM once, then L2-hits (proven: FETCH 403->107 MB).
    const int flat = blockIdx.x;
    const int p = (flat & 7) * NCOL_TILES + (flat >> 3);
    const int rowBase = (p & 7) * 128;      // 8 row tiles
    const int colBase = (p >> 3) * 128;     // 782 col tiles

    if (tid < 128) {
        sF[tid]  = ftl[rowBase + tid];
        sF1[tid] = ftl1[rowBase + tid];
        sLab[tid] = labels[rowBase + tid];
    }

    const int wave = tid >> 6;
    const int lane = tid & 63;
    const int wm = wave >> 1, wn = wave & 1;
    const int rowA0 = tid >> 2;             // staging: chunk = tid, row = tid/4
    const int kc0 = (tid & 3) * 8;

    floatx4 acc[4][4] = {};

    const unsigned short* gA = A + (size_t)(rowBase + rowA0) * EMB + kc0;
    const unsigned short* gB = B + (size_t)(colBase + rowA0) * EMB + kc0;
    unsigned short* lA0 = &ldsA[tid * 8];
    unsigned short* lA1 = &ldsA[tid * 8 + 2048];
    unsigned short* lB0 = &ldsB[tid * 8];
    unsigned short* lB1 = &ldsB[tid * 8 + 2048];

    const int rA = (wm * 64 + (lane & 15)) * 32 + (lane >> 4) * 8;
    const int rB = (wn * 64 + (lane & 15)) * 32 + (lane >> 4) * 8;

    for (int kk = 0; kk < EMB; kk += 32) {
        load16(gA + kk, lA0);
        load16(gA + kk + 64 * EMB, lA1);
        load16(gB + kk, lB0);
        load16(gB + kk + 64 * EMB, lB1);
        __syncthreads();
        bf16x8 af[4], bf[4];
        #pragma unroll
        for (int mi = 0; mi < 4; mi++) af[mi] = *(const bf16x8*)&ldsA[rA + mi * 16 * 32];
        #pragma unroll
        for (int ni = 0; ni < 4; ni++) bf[ni] = *(const bf16x8*)&ldsB[rB + ni * 16 * 32];
        // swapped operands: lane&15 = batch row, (lane>>4)*4 + r = class col
        #pragma unroll
        for (int mi = 0; mi < 4; mi++)
            #pragma unroll
            for (int ni = 0; ni < 4; ni++)
                acc[mi][ni] = __builtin_amdgcn_mfma_f32_16x16x32_bf16(bf[ni], af[mi], acc[mi][ni], 0, 0, 0);
        __syncthreads();
    }

    // epilogue: clip, masks, counts, label override, scale, float4 nt store
    unsigned cH = 0, cN = 0;
    #pragma unroll
    for (int mi = 0; mi < 4; mi++) {
        const int row = wm * 64 + mi * 16 + (lane & 15);
        const float F = sF[row], F1 = sF1[row];
        const int lab = sLab[row];
        float* orow = out + (size_t)(rowBase + row) * NUM_CLASS;
        #pragma unroll
        for (int ni = 0; ni < 4; ni++) {
            const int col = colBase + wn * 64 + ni * 16 + (lane >> 4) * 4;
            if (col < NUM_CLASS) {     // 100000 % 4 == 0: chunk fully in or out
                floatx4 a = acc[mi][ni];
                floatx4 v;
                #pragma unroll
                for (int r = 0; r < 4; r++) {
                    float lg = fminf(1.0f, fmaxf(-1.0f, a[r]));
                    bool h = lg > F, n = lg > F1;
                    cH += h; cN += n;
                    float val = n ? fmaxf(lg, 1e-30f) : (h ? lg * T_HARD : lg);
                    if (col + r == lab) val = F;
                    v[r] = val * S_SCALE;
                }
                __builtin_nontemporal_store(v, (floatx4*)(orow + col));
            }
        }
    }
    for (int off = 32; off; off >>= 1) { cH += __shfl_down(cH, off); cN += __shfl_down(cN, off); }
    if (lane == 0) { sCnt[wave] = cH; sCnt[4 + wave] = cN; }
    __syncthreads();
    if (tid == 0) {
        atomicAdd(&cnt[0], sCnt[0] + sCnt[1] + sCnt[2] + sCnt[3]);
        atomicAdd(&cnt[1], sCnt[4] + sCnt[5] + sCnt[6] + sCnt[7]);
    }
}

// ---- Kernel 5: finalize scalar outputs (separate launch: no fence in k_gemm) ----
__global__ void k_final(const unsigned* __restrict__ cnt, float* __restrict__ o) {
    unsigned hard_cnt = cnt[0], noise_num = cnt[1];
    const unsigned num_all = (unsigned)BATCH * (unsigned)NUM_CLASS;   // 102,400,000
    unsigned easy = num_all - hard_cnt;
    unsigned hard_num = hard_cnt - noise_num;
    float phi = ((float)easy / (float)num_all) * 0.01f;
    o[0] = (float)easy;
    o[1] = (float)noise_num;
    o[2] = (float)hard_num;
    o[3] = phi;
}

extern "C" void kernel_launch(void* const* d_in, const int* in_sizes, int n_in,
                              void* d_out, int out_size, void* d_ws, size_t ws_size,
                              hipStream_t stream) {
    const float* emb = (const float*)d_in[0];
    const float* wgt = (const float*)d_in[1];
    const int* labels = (const int*)d_in[2];
    float* out = (float*)d_out;
    char* ws = (char*)d_ws;

    unsigned* cnt = (unsigned*)ws;                           // 64 B
    float* ftl  = (float*)(ws + 64);                         // 4 KB
    float* ftl1 = (float*)(ws + 8192);                       // 4 KB
    unsigned short* ne = (unsigned short*)(ws + 16384);      // 1 MB
    unsigned short* nw = (unsigned short*)(ws + (1 << 21));  // ~102.5 MB

    hipMemsetAsync(cnt, 0, 64, stream);
    k_embed<<<BATCH, 256, 0, stream>>>(emb, ne);
    k_tl<<<BATCH / 4, 256, 0, stream>>>(ne, wgt, labels, ftl, ftl1);
    k_weight<<<NUM_CLASS_PAD / 4, 256, 0, stream>>>(wgt, nw);
    k_gemm<<<GRID_X, 256, 0, stream>>>(ne, nw, ftl, ftl1, labels, out, cnt);
    k_final<<<1, 1, 0, stream>>>(cnt, out + (size_t)BATCH * NUM_CLASS);
}

// Round 5
// 761.221 us; speedup vs baseline: 1.4106x; 1.0032x over previous
//
#include <hip/hip_runtime.h>
#include <hip/hip_bf16.h>
#include <stdint.h>

#define NUM_CLASS 100000
#define NUM_CLASS_PAD 100096
#define EMB 512
#define BATCH 1024
#define S_SCALE 64.0f
#define T_HARD 1.2f            // T + 1
#define COS_M   0.8775825618903728f
#define SIN_M   0.479425538604203f
#define THETA_C (-0.8775825618903728f)   // cos(pi - M)
#define SINMM   0.2397127693021015f      // sin(pi - M) * M
#define COS_M1  0.9800665778412416f
#define SIN_M1  0.19866933079506122f
#define SINMM1  (-0.039733866159012244f) // sin(-M1) * M1

#define NCOL_TILES 782
#define GRID_X (8 * NCOL_TILES)          // 6256 blocks

typedef __attribute__((ext_vector_type(8))) short bf16x8;
typedef __attribute__((ext_vector_type(4))) float floatx4;

__device__ __forceinline__ unsigned short f2bf(float f) {
    union { float f; unsigned u; } v; v.f = f;
    unsigned r = v.u + 0x7fffu + ((v.u >> 16) & 1u);
    return (unsigned short)(r >> 16);
}
__device__ __forceinline__ float blo(unsigned u) {
    union { unsigned v; float f; } c; c.v = u << 16; return c.f;
}
__device__ __forceinline__ float bhi(unsigned u) {
    union { unsigned v; float f; } c; c.v = u & 0xffff0000u; return c.f;
}
__device__ __forceinline__ void load16(const void* g, void* l) {
    __builtin_amdgcn_global_load_lds(
        (const __attribute__((address_space(1))) void*)g,
        (__attribute__((address_space(3))) void*)l, 16, 0, 0);
}

// ---- Kernel 1: normalize embeddings -> bf16 ----
__global__ void k_embed(const float* __restrict__ emb, unsigned short* __restrict__ ne) {
    int row = blockIdx.x;            // 1024
    int t = threadIdx.x;             // 256, 2 floats each
    float2 v = ((const float2*)(emb + row * EMB))[t];
    float ss = v.x * v.x + v.y * v.y;
    __shared__ float red[4];
    for (int off = 32; off; off >>= 1) ss += __shfl_down(ss, off);
    if ((t & 63) == 0) red[t >> 6] = ss;
    __syncthreads();
    float inv = rsqrtf(red[0] + red[1] + red[2] + red[3]);
    unsigned b0 = f2bf(v.x * inv), b1 = f2bf(v.y * inv);
    ((unsigned*)(ne + row * EMB))[t] = b0 | (b1 << 16);
}

// ---- Kernel 2: normalize weights -> bf16 (one wave per row, padded to 100096) ----
// Plain stores (not nontemporal): nw stays L2/L3-resident for k_gemm to re-read.
__global__ void k_weight(const float* __restrict__ w, unsigned short* __restrict__ nw) {
    int r = blockIdx.x * 4 + (threadIdx.x >> 6);
    int L = threadIdx.x & 63;
    uint4* dst = (uint4*)(nw + (size_t)r * EMB + L * 8);
    if (r >= NUM_CLASS) { *dst = make_uint4(0, 0, 0, 0); return; }
    const float4* src = (const float4*)(w + (size_t)r * EMB + L * 8);
    float4 a = src[0], b = src[1];
    float ss = a.x*a.x + a.y*a.y + a.z*a.z + a.w*a.w
             + b.x*b.x + b.y*b.y + b.z*b.z + b.w*b.w;
    for (int off = 32; off; off >>= 1) ss += __shfl_down(ss, off);
    ss = __shfl(ss, 0);
    float inv = rsqrtf(ss);
    uint4 o;
    o.x = (unsigned)f2bf(a.x*inv) | ((unsigned)f2bf(a.y*inv) << 16);
    o.y = (unsigned)f2bf(a.z*inv) | ((unsigned)f2bf(a.w*inv) << 16);
    o.z = (unsigned)f2bf(b.x*inv) | ((unsigned)f2bf(b.y*inv) << 16);
    o.w = (unsigned)f2bf(b.z*inv) | ((unsigned)f2bf(b.w*inv) << 16);
    *dst = o;
}

// ---- Kernel 3: target logits from RAW fp32 weights (one wave per row) ----
__global__ void k_tl(const unsigned short* __restrict__ ne, const float* __restrict__ w,
                     const int* __restrict__ labels, float* __restrict__ ftl, float* __restrict__ ftl1) {
    int b = blockIdx.x * 4 + (threadIdx.x >> 6);
    int L = threadIdx.x & 63;
    int lab = labels[b];
    uint4 ua = *(const uint4*)(ne + (size_t)b * EMB + L * 8);
    const float4* wp = (const float4*)(w + (size_t)lab * EMB + L * 8);
    float4 w0 = wp[0], w1 = wp[1];
    float ss = w0.x*w0.x + w0.y*w0.y + w0.z*w0.z + w0.w*w0.w
             + w1.x*w1.x + w1.y*w1.y + w1.z*w1.z + w1.w*w1.w;
    float s = blo(ua.x)*w0.x + bhi(ua.x)*w0.y + blo(ua.y)*w0.z + bhi(ua.y)*w0.w
            + blo(ua.z)*w1.x + bhi(ua.z)*w1.y + blo(ua.w)*w1.z + bhi(ua.w)*w1.w;
    for (int off = 32; off; off >>= 1) {
        s  += __shfl_down(s, off);
        ss += __shfl_down(ss, off);
    }
    if (L == 0) {
        float tl = s * rsqrtf(ss);
        tl = fminf(1.0f, fmaxf(-1.0f, tl));
        float st = sqrtf(fmaxf(0.0f, 1.0f - tl * tl));
        float cos_tm  = tl * COS_M  - st * SIN_M;
        float cos_tm1 = tl * COS_M1 - st * SIN_M1;
        float f  = (tl > THETA_C)  ? cos_tm  : (tl - SINMM);
        float f1 = (tl <= COS_M1)  ? cos_tm1 : (tl + SINMM1);
        ftl[b] = f;
        ftl1[b] = f1;
    }
}

// ---- Kernel 4: bf16 MFMA GEMM 128x128, double-buffered LDS + counted vmcnt ----
// One raw s_barrier per K-step; prefetch loads stay in flight across the barrier
// (s_waitcnt vmcnt(4) waits only the CURRENT tile's 4 load_lds). This removes the
// vmcnt(0) full-drain that made round-4 latency-bound (1.8k+ cy/K-step of stall).
__global__ __launch_bounds__(256, 4)
void k_gemm(const unsigned short* __restrict__ A,   // ne [1024][512]
            const unsigned short* __restrict__ B,   // nw [100096][512]
            const float* __restrict__ ftl, const float* __restrict__ ftl1,
            const int* __restrict__ labels,
            float* __restrict__ out, unsigned* __restrict__ cnt) {
    __shared__ unsigned short ldsA[2 * 128 * 32];   // 16 KB, double-buffered
    __shared__ unsigned short ldsB[2 * 128 * 32];   // 16 KB
    __shared__ float sF[128], sF1[128];
    __shared__ int sLab[128];
    __shared__ unsigned sCnt[8];

    const int tid = threadIdx.x;
    // bijective XCD swizzle: all 8 row-tiles of a col-tile land on one XCD
    // (proven: FETCH 403->55 MB).
    const int flat = blockIdx.x;
    const int p = (flat & 7) * NCOL_TILES + (flat >> 3);
    const int rowBase = (p & 7) * 128;      // 8 row tiles
    const int colBase = (p >> 3) * 128;     // 782 col tiles

    if (tid < 128) {
        sF[tid]  = ftl[rowBase + tid];
        sF1[tid] = ftl1[rowBase + tid];
        sLab[tid] = labels[rowBase + tid];
    }

    const int wave = tid >> 6;
    const int lane = tid & 63;
    const int wm = wave >> 1, wn = wave & 1;
    const int rowA0 = tid >> 2;             // staging: chunk = tid, row = tid/4
    const int kc0 = (tid & 3) * 8;

    floatx4 acc[4][4] = {};

    const unsigned short* gA = A + (size_t)(rowBase + rowA0) * EMB + kc0;
    const unsigned short* gB = B + (size_t)(colBase + rowA0) * EMB + kc0;

    const int rA = (wm * 64 + (lane & 15)) * 32 + (lane >> 4) * 8;
    const int rB = (wn * 64 + (lane & 15)) * 32 + (lane >> 4) * 8;

    __syncthreads();   // sF/sF1/sLab visible; before any prefetch (full drain ok here)

#define ISSUE(kkv, buf) do {                                            \
        load16(gA + (kkv), &ldsA[(buf) * 4096 + tid * 8]);              \
        load16(gA + (kkv) + 64 * EMB, &ldsA[(buf) * 4096 + 2048 + tid * 8]); \
        load16(gB + (kkv), &ldsB[(buf) * 4096 + tid * 8]);              \
        load16(gB + (kkv) + 64 * EMB, &ldsB[(buf) * 4096 + 2048 + tid * 8]); \
    } while (0)

    ISSUE(0, 0);                            // prologue: K-step 0 into buffer 0

    #pragma unroll
    for (int t = 0; t < 16; ++t) {
        const int kk = t * 32;
        const int buf = t & 1;
        // barrier FIRST: guarantees every wave consumed buf^1's previous contents
        // before we overwrite it with the next prefetch.
        __builtin_amdgcn_s_barrier();
        if (t + 1 < 16) {
            ISSUE(kk + 32, buf ^ 1);
            // wait current tile's 4 loads; leave the 4 prefetch loads in flight
            asm volatile("s_waitcnt vmcnt(4)" ::: "memory");
        } else {
            asm volatile("s_waitcnt vmcnt(0)" ::: "memory");
        }
        bf16x8 af[4], bf[4];
        #pragma unroll
        for (int mi = 0; mi < 4; mi++) af[mi] = *(const bf16x8*)&ldsA[buf * 4096 + rA + mi * 512];
        #pragma unroll
        for (int ni = 0; ni < 4; ni++) bf[ni] = *(const bf16x8*)&ldsB[buf * 4096 + rB + ni * 512];
        // swapped operands: lane&15 = batch row, (lane>>4)*4 + r = class col
        #pragma unroll
        for (int mi = 0; mi < 4; mi++)
            #pragma unroll
            for (int ni = 0; ni < 4; ni++)
                acc[mi][ni] = __builtin_amdgcn_mfma_f32_16x16x32_bf16(bf[ni], af[mi], acc[mi][ni], 0, 0, 0);
    }
#undef ISSUE

    // epilogue: clip, masks, counts, label override, scale, float4 nt store
    unsigned cH = 0, cN = 0;
    #pragma unroll
    for (int mi = 0; mi < 4; mi++) {
        const int row = wm * 64 + mi * 16 + (lane & 15);
        const float F = sF[row], F1 = sF1[row];
        const int lab = sLab[row];
        float* orow = out + (size_t)(rowBase + row) * NUM_CLASS;
        #pragma unroll
        for (int ni = 0; ni < 4; ni++) {
            const int col = colBase + wn * 64 + ni * 16 + (lane >> 4) * 4;
            if (col < NUM_CLASS) {     // 100000 % 4 == 0: chunk fully in or out
                floatx4 a = acc[mi][ni];
                floatx4 v;
                #pragma unroll
                for (int r = 0; r < 4; r++) {
                    float lg = fminf(1.0f, fmaxf(-1.0f, a[r]));
                    bool h = lg > F, n = lg > F1;
                    cH += h; cN += n;
                    float val = n ? fmaxf(lg, 1e-30f) : (h ? lg * T_HARD : lg);
                    if (col + r == lab) val = F;
                    v[r] = val * S_SCALE;
                }
                __builtin_nontemporal_store(v, (floatx4*)(orow + col));
            }
        }
    }
    for (int off = 32; off; off >>= 1) { cH += __shfl_down(cH, off); cN += __shfl_down(cN, off); }
    if (lane == 0) { sCnt[wave] = cH; sCnt[4 + wave] = cN; }
    __syncthreads();
    if (tid == 0) {
        atomicAdd(&cnt[0], sCnt[0] + sCnt[1] + sCnt[2] + sCnt[3]);
        atomicAdd(&cnt[1], sCnt[4] + sCnt[5] + sCnt[6] + sCnt[7]);
    }
}

// ---- Kernel 5: finalize scalar outputs (separate launch: no fence in k_gemm) ----
__global__ void k_final(const unsigned* __restrict__ cnt, float* __restrict__ o) {
    unsigned hard_cnt = cnt[0], noise_num = cnt[1];
    const unsigned num_all = (unsigned)BATCH * (unsigned)NUM_CLASS;   // 102,400,000
    unsigned easy = num_all - hard_cnt;
    unsigned hard_num = hard_cnt - noise_num;
    float phi = ((float)easy / (float)num_all) * 0.01f;
    o[0] = (float)easy;
    o[1] = (float)noise_num;
    o[2] = (float)hard_num;
    o[3] = phi;
}

extern "C" void kernel_launch(void* const* d_in, const int* in_sizes, int n_in,
                              void* d_out, int out_size, void* d_ws, size_t ws_size,
                              hipStream_t stream) {
    const float* emb = (const float*)d_in[0];
    const float* wgt = (const float*)d_in[1];
    const int* labels = (const int*)d_in[2];
    float* out = (float*)d_out;
    char* ws = (char*)d_ws;

    unsigned* cnt = (unsigned*)ws;                           // 64 B
    float* ftl  = (float*)(ws + 64);                         // 4 KB
    float* ftl1 = (float*)(ws + 8192);                       // 4 KB
    unsigned short* ne = (unsigned short*)(ws + 16384);      // 1 MB
    unsigned short* nw = (unsigned short*)(ws + (1 << 21));  // ~102.5 MB

    hipMemsetAsync(cnt, 0, 64, stream);
    k_embed<<<BATCH, 256, 0, stream>>>(emb, ne);
    k_tl<<<BATCH / 4, 256, 0, stream>>>(ne, wgt, labels, ftl, ftl1);
    k_weight<<<NUM_CLASS_PAD / 4, 256, 0, stream>>>(wgt, nw);
    k_gemm<<<GRID_X, 256, 0, stream>>>(ne, nw, ftl, ftl1, labels, out, cnt);
    k_final<<<1, 1, 0, stream>>>(cnt, out + (size_t)BATCH * NUM_CLASS);
}

// Round 6
// 758.778 us; speedup vs baseline: 1.4151x; 1.0032x over previous
//
#include <hip/hip_runtime.h>
#include <hip/hip_bf16.h>
#include <stdint.h>

#define NUM_CLASS 100000
#define NUM_CLASS_PAD 100096
#define EMB 512
#define BATCH 1024
#define S_SCALE 64.0f
#define T_HARD 1.2f            // T + 1
#define COS_M   0.8775825618903728f
#define SIN_M   0.479425538604203f
#define THETA_C (-0.8775825618903728f)   // cos(pi - M)
#define SINMM   0.2397127693021015f      // sin(pi - M) * M
#define COS_M1  0.9800665778412416f
#define SIN_M1  0.19866933079506122f
#define SINMM1  (-0.039733866159012244f) // sin(-M1) * M1

#define NCOL_TILES 782
#define GRID_X (8 * NCOL_TILES)          // 6256 blocks

typedef __attribute__((ext_vector_type(8))) short bf16x8;
typedef __attribute__((ext_vector_type(4))) float floatx4;

__device__ __forceinline__ unsigned short f2bf(float f) {
    union { float f; unsigned u; } v; v.f = f;
    unsigned r = v.u + 0x7fffu + ((v.u >> 16) & 1u);
    return (unsigned short)(r >> 16);
}
__device__ __forceinline__ float blo(unsigned u) {
    union { unsigned v; float f; } c; c.v = u << 16; return c.f;
}
__device__ __forceinline__ float bhi(unsigned u) {
    union { unsigned v; float f; } c; c.v = u & 0xffff0000u; return c.f;
}
__device__ __forceinline__ void load16(const void* g, void* l) {
    __builtin_amdgcn_global_load_lds(
        (const __attribute__((address_space(1))) void*)g,
        (__attribute__((address_space(3))) void*)l, 16, 0, 0);
}

// ---- Kernel 1: normalize embeddings -> bf16 ----
__global__ void k_embed(const float* __restrict__ emb, unsigned short* __restrict__ ne) {
    int row = blockIdx.x;            // 1024
    int t = threadIdx.x;             // 256, 2 floats each
    float2 v = ((const float2*)(emb + row * EMB))[t];
    float ss = v.x * v.x + v.y * v.y;
    __shared__ float red[4];
    for (int off = 32; off; off >>= 1) ss += __shfl_down(ss, off);
    if ((t & 63) == 0) red[t >> 6] = ss;
    __syncthreads();
    float inv = rsqrtf(red[0] + red[1] + red[2] + red[3]);
    unsigned b0 = f2bf(v.x * inv), b1 = f2bf(v.y * inv);
    ((unsigned*)(ne + row * EMB))[t] = b0 | (b1 << 16);
}

// ---- Kernel 2: normalize weights -> bf16 (one wave per row, padded to 100096) ----
// Plain stores (not nontemporal): nw stays L2/L3-resident for k_gemm to re-read.
__global__ void k_weight(const float* __restrict__ w, unsigned short* __restrict__ nw) {
    int r = blockIdx.x * 4 + (threadIdx.x >> 6);
    int L = threadIdx.x & 63;
    uint4* dst = (uint4*)(nw + (size_t)r * EMB + L * 8);
    if (r >= NUM_CLASS) { *dst = make_uint4(0, 0, 0, 0); return; }
    const float4* src = (const float4*)(w + (size_t)r * EMB + L * 8);
    float4 a = src[0], b = src[1];
    float ss = a.x*a.x + a.y*a.y + a.z*a.z + a.w*a.w
             + b.x*b.x + b.y*b.y + b.z*b.z + b.w*b.w;
    for (int off = 32; off; off >>= 1) ss += __shfl_down(ss, off);
    ss = __shfl(ss, 0);
    float inv = rsqrtf(ss);
    uint4 o;
    o.x = (unsigned)f2bf(a.x*inv) | ((unsigned)f2bf(a.y*inv) << 16);
    o.y = (unsigned)f2bf(a.z*inv) | ((unsigned)f2bf(a.w*inv) << 16);
    o.z = (unsigned)f2bf(b.x*inv) | ((unsigned)f2bf(b.y*inv) << 16);
    o.w = (unsigned)f2bf(b.z*inv) | ((unsigned)f2bf(b.w*inv) << 16);
    *dst = o;
}

// ---- Kernel 3: target logits from RAW fp32 weights (one wave per row) ----
__global__ void k_tl(const unsigned short* __restrict__ ne, const float* __restrict__ w,
                     const int* __restrict__ labels, float* __restrict__ ftl, float* __restrict__ ftl1) {
    int b = blockIdx.x * 4 + (threadIdx.x >> 6);
    int L = threadIdx.x & 63;
    int lab = labels[b];
    uint4 ua = *(const uint4*)(ne + (size_t)b * EMB + L * 8);
    const float4* wp = (const float4*)(w + (size_t)lab * EMB + L * 8);
    float4 w0 = wp[0], w1 = wp[1];
    float ss = w0.x*w0.x + w0.y*w0.y + w0.z*w0.z + w0.w*w0.w
             + w1.x*w1.x + w1.y*w1.y + w1.z*w1.z + w1.w*w1.w;
    float s = blo(ua.x)*w0.x + bhi(ua.x)*w0.y + blo(ua.y)*w0.z + bhi(ua.y)*w0.w
            + blo(ua.z)*w1.x + bhi(ua.z)*w1.y + blo(ua.w)*w1.z + bhi(ua.w)*w1.w;
    for (int off = 32; off; off >>= 1) {
        s  += __shfl_down(s, off);
        ss += __shfl_down(ss, off);
    }
    if (L == 0) {
        float tl = s * rsqrtf(ss);
        tl = fminf(1.0f, fmaxf(-1.0f, tl));
        float st = sqrtf(fmaxf(0.0f, 1.0f - tl * tl));
        float cos_tm  = tl * COS_M  - st * SIN_M;
        float cos_tm1 = tl * COS_M1 - st * SIN_M1;
        float f  = (tl > THETA_C)  ? cos_tm  : (tl - SINMM);
        float f1 = (tl <= COS_M1)  ? cos_tm1 : (tl + SINMM1);
        ftl[b] = f;
        ftl1[b] = f1;
    }
}

// ---- Kernel 4: bf16 MFMA GEMM 128x128 (round-4 K-loop) + LDS-transposed epilogue ----
// Epilogue: math in-reg, stage 32x128 fp32 tile to LDS (XOR-swizzled), write back
// with 32 lanes per row -> 512-B contiguous runs, full 128-B lines (was 64-B
// scatter at 1.9 TB/s with 38% write amplification).
__global__ __launch_bounds__(256, 4)
void k_gemm(const unsigned short* __restrict__ A,   // ne [1024][512]
            const unsigned short* __restrict__ B,   // nw [100096][512]
            const float* __restrict__ ftl, const float* __restrict__ ftl1,
            const int* __restrict__ labels,
            float* __restrict__ out, unsigned* __restrict__ cnt) {
    __shared__ __align__(16) unsigned short ldsAB[8192];   // 16 KB: A tile + B tile
    __shared__ float sF[128], sF1[128];
    __shared__ int sLab[128];
    __shared__ unsigned sCnt[8];

    unsigned short* ldsA = ldsAB;            // [128][32] bf16
    unsigned short* ldsB = ldsAB + 4096;     // [128][32] bf16
    floatx4* ldsE4 = (floatx4*)ldsAB;        // epilogue reuse: [32 rows][32 float4]

    const int tid = threadIdx.x;
    // bijective XCD swizzle: all 8 row-tiles of a col-tile land on one XCD
    // (proven: FETCH 403->55 MB).
    const int flat = blockIdx.x;
    const int p = (flat & 7) * NCOL_TILES + (flat >> 3);
    const int rowBase = (p & 7) * 128;      // 8 row tiles
    const int colBase = (p >> 3) * 128;     // 782 col tiles

    if (tid < 128) {
        sF[tid]  = ftl[rowBase + tid];
        sF1[tid] = ftl1[rowBase + tid];
        sLab[tid] = labels[rowBase + tid];
    }

    const int wave = tid >> 6;
    const int lane = tid & 63;
    const int wm = wave >> 1, wn = wave & 1;
    const int rowA0 = tid >> 2;             // staging: chunk = tid, row = tid/4
    const int kc0 = (tid & 3) * 8;

    floatx4 acc[4][4] = {};

    const unsigned short* gA = A + (size_t)(rowBase + rowA0) * EMB + kc0;
    const unsigned short* gB = B + (size_t)(colBase + rowA0) * EMB + kc0;
    unsigned short* lA0 = &ldsA[tid * 8];
    unsigned short* lA1 = &ldsA[tid * 8 + 2048];
    unsigned short* lB0 = &ldsB[tid * 8];
    unsigned short* lB1 = &ldsB[tid * 8 + 2048];

    const int rA = (wm * 64 + (lane & 15)) * 32 + (lane >> 4) * 8;
    const int rB = (wn * 64 + (lane & 15)) * 32 + (lane >> 4) * 8;

    for (int kk = 0; kk < EMB; kk += 32) {
        load16(gA + kk, lA0);
        load16(gA + kk + 64 * EMB, lA1);
        load16(gB + kk, lB0);
        load16(gB + kk + 64 * EMB, lB1);
        __syncthreads();
        bf16x8 af[4], bf[4];
        #pragma unroll
        for (int mi = 0; mi < 4; mi++) af[mi] = *(const bf16x8*)&ldsA[rA + mi * 16 * 32];
        #pragma unroll
        for (int ni = 0; ni < 4; ni++) bf[ni] = *(const bf16x8*)&ldsB[rB + ni * 16 * 32];
        // swapped operands: lane&15 = batch row, (lane>>4)*4 + r = class col
        #pragma unroll
        for (int mi = 0; mi < 4; mi++)
            #pragma unroll
            for (int ni = 0; ni < 4; ni++)
                acc[mi][ni] = __builtin_amdgcn_mfma_f32_16x16x32_bf16(bf[ni], af[mi], acc[mi][ni], 0, 0, 0);
        __syncthreads();
    }
    // all waves past final sync => all LDS reads done; safe to reuse ldsAB

    // epilogue: per mi-group (32 rows x 128 cols = 16 KB), math in-reg ->
    // swizzled LDS stage -> contiguous 512-B-per-row write-back.
    unsigned cH = 0, cN = 0;
    const int r32 = wm * 16 + (lane & 15);      // LDS row slot 0..31
    #pragma unroll
    for (int mi = 0; mi < 4; mi++) {
        if (mi) __syncthreads();                // protect previous read-back
        const int row = wm * 64 + mi * 16 + (lane & 15);
        const float F = sF[row], F1 = sF1[row];
        const int lab = sLab[row];
        #pragma unroll
        for (int ni = 0; ni < 4; ni++) {
            const int colL = wn * 64 + ni * 16 + (lane >> 4) * 4;
            const int col = colBase + colL;
            const bool valid = col < NUM_CLASS;  // 100000 % 4 == 0
            floatx4 a = acc[mi][ni];
            floatx4 v;
            #pragma unroll
            for (int r = 0; r < 4; r++) {
                float lg = fminf(1.0f, fmaxf(-1.0f, a[r]));
                bool h = lg > F, n = lg > F1;
                cH += (h && valid); cN += (n && valid);
                float val = n ? fmaxf(lg, 1e-30f) : (h ? lg * T_HARD : lg);
                if (col + r == lab) val = F;
                v[r] = val * S_SCALE;
            }
            const int c4 = colL >> 2;            // 0..31
            ldsE4[r32 * 32 + (c4 ^ (r32 & 7))] = v;
        }
        __syncthreads();
        // write-back: 1024 float4s, 4/thread; 32 consecutive lanes = one row (512 B)
        #pragma unroll
        for (int c = 0; c < 4; c++) {
            const int idx = c * 256 + tid;
            const int rr = idx >> 5;             // 0..31
            const int c4 = idx & 31;
            const int gcol = colBase + c4 * 4;
            if (gcol < NUM_CLASS) {
                const int grow = rowBase + (rr >> 4) * 64 + mi * 16 + (rr & 15);
                floatx4 v = ldsE4[rr * 32 + (c4 ^ (rr & 7))];
                __builtin_nontemporal_store(v, (floatx4*)(out + (size_t)grow * NUM_CLASS + gcol));
            }
        }
    }

    for (int off = 32; off; off >>= 1) { cH += __shfl_down(cH, off); cN += __shfl_down(cN, off); }
    if (lane == 0) { sCnt[wave] = cH; sCnt[4 + wave] = cN; }
    __syncthreads();
    if (tid == 0) {
        atomicAdd(&cnt[0], sCnt[0] + sCnt[1] + sCnt[2] + sCnt[3]);
        atomicAdd(&cnt[1], sCnt[4] + sCnt[5] + sCnt[6] + sCnt[7]);
    }
}

// ---- Kernel 5: finalize scalar outputs (separate launch: no fence in k_gemm) ----
__global__ void k_final(const unsigned* __restrict__ cnt, float* __restrict__ o) {
    unsigned hard_cnt = cnt[0], noise_num = cnt[1];
    const unsigned num_all = (unsigned)BATCH * (unsigned)NUM_CLASS;   // 102,400,000
    unsigned easy = num_all - hard_cnt;
    unsigned hard_num = hard_cnt - noise_num;
    float phi = ((float)easy / (float)num_all) * 0.01f;
    o[0] = (float)easy;
    o[1] = (float)noise_num;
    o[2] = (float)hard_num;
    o[3] = phi;
}

extern "C" void kernel_launch(void* const* d_in, const int* in_sizes, int n_in,
                              void* d_out, int out_size, void* d_ws, size_t ws_size,
                              hipStream_t stream) {
    const float* emb = (const float*)d_in[0];
    const float* wgt = (const float*)d_in[1];
    const int* labels = (const int*)d_in[2];
    float* out = (float*)d_out;
    char* ws = (char*)d_ws;

    unsigned* cnt = (unsigned*)ws;                           // 64 B
    float* ftl  = (float*)(ws + 64);                         // 4 KB
    float* ftl1 = (float*)(ws + 8192);                       // 4 KB
    unsigned short* ne = (unsigned short*)(ws + 16384);      // 1 MB
    unsigned short* nw = (unsigned short*)(ws + (1 << 21));  // ~102.5 MB

    hipMemsetAsync(cnt, 0, 64, stream);
    k_embed<<<BATCH, 256, 0, stream>>>(emb, ne);
    k_tl<<<BATCH / 4, 256, 0, stream>>>(ne, wgt, labels, ftl, ftl1);
    k_weight<<<NUM_CLASS_PAD / 4, 256, 0, stream>>>(wgt, nw);
    k_gemm<<<GRID_X, 256, 0, stream>>>(ne, nw, ftl, ftl1, labels, out, cnt);
    k_final<<<1, 1, 0, stream>>>(cnt, out + (size_t)BATCH * NUM_CLASS);
}

// Round 7
// 750.601 us; speedup vs baseline: 1.4305x; 1.0109x over previous
//
#include <hip/hip_runtime.h>
#include <hip/hip_bf16.h>
#include <stdint.h>

#define NUM_CLASS 100000
#define NUM_CLASS_PAD 100096
#define EMB 512
#define BATCH 1024
#define S_SCALE 64.0f
#define T_HARD 1.2f            // T + 1
#define COS_M   0.8775825618903728f
#define SIN_M   0.479425538604203f
#define THETA_C (-0.8775825618903728f)   // cos(pi - M)
#define SINMM   0.2397127693021015f      // sin(pi - M) * M
#define COS_M1  0.9800665778412416f
#define SIN_M1  0.19866933079506122f
#define SINMM1  (-0.039733866159012244f) // sin(-M1) * M1

#define NCOL_TILES 782
#define GRID_X (8 * NCOL_TILES)          // 6256 blocks

typedef __attribute__((ext_vector_type(8))) short bf16x8;
typedef __attribute__((ext_vector_type(4))) float floatx4;

__device__ __forceinline__ unsigned short f2bf(float f) {
    union { float f; unsigned u; } v; v.f = f;
    unsigned r = v.u + 0x7fffu + ((v.u >> 16) & 1u);
    return (unsigned short)(r >> 16);
}
__device__ __forceinline__ float blo(unsigned u) {
    union { unsigned v; float f; } c; c.v = u << 16; return c.f;
}
__device__ __forceinline__ float bhi(unsigned u) {
    union { unsigned v; float f; } c; c.v = u & 0xffff0000u; return c.f;
}
__device__ __forceinline__ void load16(const void* g, void* l) {
    __builtin_amdgcn_global_load_lds(
        (const __attribute__((address_space(1))) void*)g,
        (__attribute__((address_space(3))) void*)l, 16, 0, 0);
}

// ---- Kernel 1: normalize embeddings -> bf16 ----
__global__ void k_embed(const float* __restrict__ emb, unsigned short* __restrict__ ne) {
    int row = blockIdx.x;            // 1024
    int t = threadIdx.x;             // 256, 2 floats each
    float2 v = ((const float2*)(emb + row * EMB))[t];
    float ss = v.x * v.x + v.y * v.y;
    __shared__ float red[4];
    for (int off = 32; off; off >>= 1) ss += __shfl_down(ss, off);
    if ((t & 63) == 0) red[t >> 6] = ss;
    __syncthreads();
    float inv = rsqrtf(red[0] + red[1] + red[2] + red[3]);
    unsigned b0 = f2bf(v.x * inv), b1 = f2bf(v.y * inv);
    ((unsigned*)(ne + row * EMB))[t] = b0 | (b1 << 16);
}

// ---- Kernel 2: normalize weights -> bf16 (one wave per row, padded to 100096) ----
// Plain stores (not nontemporal): nw stays L2/L3-resident for k_gemm to re-read.
__global__ void k_weight(const float* __restrict__ w, unsigned short* __restrict__ nw) {
    int r = blockIdx.x * 4 + (threadIdx.x >> 6);
    int L = threadIdx.x & 63;
    uint4* dst = (uint4*)(nw + (size_t)r * EMB + L * 8);
    if (r >= NUM_CLASS) { *dst = make_uint4(0, 0, 0, 0); return; }
    const float4* src = (const float4*)(w + (size_t)r * EMB + L * 8);
    float4 a = src[0], b = src[1];
    float ss = a.x*a.x + a.y*a.y + a.z*a.z + a.w*a.w
             + b.x*b.x + b.y*b.y + b.z*b.z + b.w*b.w;
    for (int off = 32; off; off >>= 1) ss += __shfl_down(ss, off);
    ss = __shfl(ss, 0);
    float inv = rsqrtf(ss);
    uint4 o;
    o.x = (unsigned)f2bf(a.x*inv) | ((unsigned)f2bf(a.y*inv) << 16);
    o.y = (unsigned)f2bf(a.z*inv) | ((unsigned)f2bf(a.w*inv) << 16);
    o.z = (unsigned)f2bf(b.x*inv) | ((unsigned)f2bf(b.y*inv) << 16);
    o.w = (unsigned)f2bf(b.z*inv) | ((unsigned)f2bf(b.w*inv) << 16);
    *dst = o;
}

// ---- Kernel 3: target logits from RAW fp32 weights (one wave per row) ----
__global__ void k_tl(const unsigned short* __restrict__ ne, const float* __restrict__ w,
                     const int* __restrict__ labels, float* __restrict__ ftl, float* __restrict__ ftl1) {
    int b = blockIdx.x * 4 + (threadIdx.x >> 6);
    int L = threadIdx.x & 63;
    int lab = labels[b];
    uint4 ua = *(const uint4*)(ne + (size_t)b * EMB + L * 8);
    const float4* wp = (const float4*)(w + (size_t)lab * EMB + L * 8);
    float4 w0 = wp[0], w1 = wp[1];
    float ss = w0.x*w0.x + w0.y*w0.y + w0.z*w0.z + w0.w*w0.w
             + w1.x*w1.x + w1.y*w1.y + w1.z*w1.z + w1.w*w1.w;
    float s = blo(ua.x)*w0.x + bhi(ua.x)*w0.y + blo(ua.y)*w0.z + bhi(ua.y)*w0.w
            + blo(ua.z)*w1.x + bhi(ua.z)*w1.y + blo(ua.w)*w1.z + bhi(ua.w)*w1.w;
    for (int off = 32; off; off >>= 1) {
        s  += __shfl_down(s, off);
        ss += __shfl_down(ss, off);
    }
    if (L == 0) {
        float tl = s * rsqrtf(ss);
        tl = fminf(1.0f, fmaxf(-1.0f, tl));
        float st = sqrtf(fmaxf(0.0f, 1.0f - tl * tl));
        float cos_tm  = tl * COS_M  - st * SIN_M;
        float cos_tm1 = tl * COS_M1 - st * SIN_M1;
        float f  = (tl > THETA_C)  ? cos_tm  : (tl - SINMM);
        float f1 = (tl <= COS_M1)  ? cos_tm1 : (tl + SINMM1);
        ftl[b] = f;
        ftl1[b] = f1;
    }
}

// ---- Kernel 4: bf16 MFMA GEMM 128x128, 3-buffer pipeline, counted vmcnt BEFORE
// barrier (T4 done right: each wave certifies its own tile-t loads landed, THEN the
// barrier publishes all waves' loads; 2 K-steps of prefetch stay in flight, never
// drained to 0 mid-loop). One barrier per K-step. LDS-transposed epilogue (round-6,
// keeps WRITE_SIZE at ~463 MB).
__global__ __launch_bounds__(256, 4)
void k_gemm(const unsigned short* __restrict__ A,   // ne [1024][512]
            const unsigned short* __restrict__ B,   // nw [100096][512]
            const float* __restrict__ ftl, const float* __restrict__ ftl1,
            const int* __restrict__ labels,
            float* __restrict__ out, unsigned* __restrict__ cnt) {
    __shared__ __align__(16) unsigned short ldsA[3 * 4096];   // 24 KB, 3 bufs [128][32]
    __shared__ __align__(16) unsigned short ldsB[3 * 4096];   // 24 KB
    __shared__ float sF[128], sF1[128];
    __shared__ int sLab[128];
    __shared__ unsigned sCnt[8];

    floatx4* ldsE4 = (floatx4*)ldsA;        // epilogue reuse: [32 rows][32 float4]

    const int tid = threadIdx.x;
    // bijective XCD swizzle: all 8 row-tiles of a col-tile land on one XCD
    // (proven: FETCH 403->55 MB).
    const int flat = blockIdx.x;
    const int p = (flat & 7) * NCOL_TILES + (flat >> 3);
    const int rowBase = (p & 7) * 128;      // 8 row tiles
    const int colBase = (p >> 3) * 128;     // 782 col tiles

    if (tid < 128) {
        sF[tid]  = ftl[rowBase + tid];
        sF1[tid] = ftl1[rowBase + tid];
        sLab[tid] = labels[rowBase + tid];
    }

    const int wave = tid >> 6;
    const int lane = tid & 63;
    const int wm = wave >> 1, wn = wave & 1;
    const int rowA0 = tid >> 2;             // staging: chunk = tid, row = tid/4
    const int kc0 = (tid & 3) * 8;

    floatx4 acc[4][4] = {};

    const unsigned short* gA = A + (size_t)(rowBase + rowA0) * EMB + kc0;
    const unsigned short* gB = B + (size_t)(colBase + rowA0) * EMB + kc0;

    const int rA = (wm * 64 + (lane & 15)) * 32 + (lane >> 4) * 8;
    const int rB = (wn * 64 + (lane & 15)) * 32 + (lane >> 4) * 8;

#define ISSUE(kkv, b) do {                                              \
        load16(gA + (kkv), &ldsA[(b) * 4096 + tid * 8]);                \
        load16(gA + (kkv) + 64 * EMB, &ldsA[(b) * 4096 + 2048 + tid * 8]); \
        load16(gB + (kkv), &ldsB[(b) * 4096 + tid * 8]);                \
        load16(gB + (kkv) + 64 * EMB, &ldsB[(b) * 4096 + 2048 + tid * 8]); \
    } while (0)

    // prologue: 2 K-steps in flight
    ISSUE(0, 0);
    ISSUE(32, 1);

    #pragma unroll
    for (int t = 0; t < 16; ++t) {
        const int kk = t * 32;
        const int buf = t % 3;
        // counted wait BEFORE barrier: own tile-t loads landed (t+1's 4 stay in
        // flight); barrier then publishes ALL waves' tile-t loads.
        if (t < 15) asm volatile("s_waitcnt vmcnt(4)" ::: "memory");
        else        asm volatile("s_waitcnt vmcnt(0)" ::: "memory");
        __builtin_amdgcn_s_barrier();
        // prefetch t+2 into the buffer last read at t-1 (protected by this barrier)
        if (t + 2 < 16) ISSUE(kk + 64, (t + 2) % 3);
        bf16x8 af[4], bf[4];
        #pragma unroll
        for (int mi = 0; mi < 4; mi++) af[mi] = *(const bf16x8*)&ldsA[buf * 4096 + rA + mi * 512];
        #pragma unroll
        for (int ni = 0; ni < 4; ni++) bf[ni] = *(const bf16x8*)&ldsB[buf * 4096 + rB + ni * 512];
        // swapped operands: lane&15 = batch row, (lane>>4)*4 + r = class col
        #pragma unroll
        for (int mi = 0; mi < 4; mi++)
            #pragma unroll
            for (int ni = 0; ni < 4; ni++)
                acc[mi][ni] = __builtin_amdgcn_mfma_f32_16x16x32_bf16(bf[ni], af[mi], acc[mi][ni], 0, 0, 0);
    }
#undef ISSUE
    __syncthreads();   // all waves done with K-loop LDS; safe to reuse for epilogue

    // epilogue: per mi-group (32 rows x 128 cols = 16 KB), math in-reg ->
    // swizzled LDS stage -> contiguous 512-B-per-row write-back.
    unsigned cH = 0, cN = 0;
    const int r32 = wm * 16 + (lane & 15);      // LDS row slot 0..31
    #pragma unroll
    for (int mi = 0; mi < 4; mi++) {
        if (mi) __syncthreads();                // protect previous read-back
        const int row = wm * 64 + mi * 16 + (lane & 15);
        const float F = sF[row], F1 = sF1[row];
        const int lab = sLab[row];
        #pragma unroll
        for (int ni = 0; ni < 4; ni++) {
            const int colL = wn * 64 + ni * 16 + (lane >> 4) * 4;
            const int col = colBase + colL;
            const bool valid = col < NUM_CLASS;  // 100000 % 4 == 0
            floatx4 a = acc[mi][ni];
            floatx4 v;
            #pragma unroll
            for (int r = 0; r < 4; r++) {
                float lg = fminf(1.0f, fmaxf(-1.0f, a[r]));
                bool h = lg > F, n = lg > F1;
                cH += (h && valid); cN += (n && valid);
                float val = n ? fmaxf(lg, 1e-30f) : (h ? lg * T_HARD : lg);
                if (col + r == lab) val = F;
                v[r] = val * S_SCALE;
            }
            const int c4 = colL >> 2;            // 0..31
            ldsE4[r32 * 32 + (c4 ^ (r32 & 7))] = v;
        }
        __syncthreads();
        // write-back: 1024 float4s, 4/thread; 32 consecutive lanes = one row (512 B)
        #pragma unroll
        for (int c = 0; c < 4; c++) {
            const int idx = c * 256 + tid;
            const int rr = idx >> 5;             // 0..31
            const int c4 = idx & 31;
            const int gcol = colBase + c4 * 4;
            if (gcol < NUM_CLASS) {
                const int grow = rowBase + (rr >> 4) * 64 + mi * 16 + (rr & 15);
                floatx4 v = ldsE4[rr * 32 + (c4 ^ (rr & 7))];
                __builtin_nontemporal_store(v, (floatx4*)(out + (size_t)grow * NUM_CLASS + gcol));
            }
        }
    }

    for (int off = 32; off; off >>= 1) { cH += __shfl_down(cH, off); cN += __shfl_down(cN, off); }
    if (lane == 0) { sCnt[wave] = cH; sCnt[4 + wave] = cN; }
    __syncthreads();
    if (tid == 0) {
        atomicAdd(&cnt[0], sCnt[0] + sCnt[1] + sCnt[2] + sCnt[3]);
        atomicAdd(&cnt[1], sCnt[4] + sCnt[5] + sCnt[6] + sCnt[7]);
    }
}

// ---- Kernel 5: finalize scalar outputs (separate launch: no fence in k_gemm) ----
__global__ void k_final(const unsigned* __restrict__ cnt, float* __restrict__ o) {
    unsigned hard_cnt = cnt[0], noise_num = cnt[1];
    const unsigned num_all = (unsigned)BATCH * (unsigned)NUM_CLASS;   // 102,400,000
    unsigned easy = num_all - hard_cnt;
    unsigned hard_num = hard_cnt - noise_num;
    float phi = ((float)easy / (float)num_all) * 0.01f;
    o[0] = (float)easy;
    o[1] = (float)noise_num;
    o[2] = (float)hard_num;
    o[3] = phi;
}

extern "C" void kernel_launch(void* const* d_in, const int* in_sizes, int n_in,
                              void* d_out, int out_size, void* d_ws, size_t ws_size,
                              hipStream_t stream) {
    const float* emb = (const float*)d_in[0];
    const float* wgt = (const float*)d_in[1];
    const int* labels = (const int*)d_in[2];
    float* out = (float*)d_out;
    char* ws = (char*)d_ws;

    unsigned* cnt = (unsigned*)ws;                           // 64 B
    float* ftl  = (float*)(ws + 64);                         // 4 KB
    float* ftl1 = (float*)(ws + 8192);                       // 4 KB
    unsigned short* ne = (unsigned short*)(ws + 16384);      // 1 MB
    unsigned short* nw = (unsigned short*)(ws + (1 << 21));  // ~102.5 MB

    hipMemsetAsync(cnt, 0, 64, stream);
    k_embed<<<BATCH, 256, 0, stream>>>(emb, ne);
    k_tl<<<BATCH / 4, 256, 0, stream>>>(ne, wgt, labels, ftl, ftl1);
    k_weight<<<NUM_CLASS_PAD / 4, 256, 0, stream>>>(wgt, nw);
    k_gemm<<<GRID_X, 256, 0, stream>>>(ne, nw, ftl, ftl1, labels, out, cnt);
    k_final<<<1, 1, 0, stream>>>(cnt, out + (size_t)BATCH * NUM_CLASS);
}

// Round 8
// 704.008 us; speedup vs baseline: 1.5252x; 1.0662x over previous
//
#include <hip/hip_runtime.h>
#include <hip/hip_bf16.h>
#include <stdint.h>

#define NUM_CLASS 100000
#define NUM_CLASS_PAD 100096
#define EMB 512
#define BATCH 1024
#define S_SCALE 64.0f
#define T_HARD 1.2f            // T + 1
#define COS_M   0.8775825618903728f
#define SIN_M   0.479425538604203f
#define THETA_C (-0.8775825618903728f)   // cos(pi - M)
#define SINMM   0.2397127693021015f      // sin(pi - M) * M
#define COS_M1  0.9800665778412416f
#define SIN_M1  0.19866933079506122f
#define SINMM1  (-0.039733866159012244f) // sin(-M1) * M1

#define BM 256
#define BN 256
#define BK 32
#define NKS 16                    // EMB / BK
#define COL_TILES 391             // 100096 / 256
#define ROW_TILES 4               // 1024 / 256
#define GRID_X (COL_TILES * ROW_TILES)   // 1564

typedef __attribute__((ext_vector_type(8))) short bf16x8;
typedef __attribute__((ext_vector_type(4))) float floatx4;

__device__ __forceinline__ unsigned short f2bf(float f) {
    union { float f; unsigned u; } v; v.f = f;
    unsigned r = v.u + 0x7fffu + ((v.u >> 16) & 1u);
    return (unsigned short)(r >> 16);
}
__device__ __forceinline__ float blo(unsigned u) {
    union { unsigned v; float f; } c; c.v = u << 16; return c.f;
}
__device__ __forceinline__ float bhi(unsigned u) {
    union { unsigned v; float f; } c; c.v = u & 0xffff0000u; return c.f;
}
__device__ __forceinline__ void load16(const void* g, void* l) {
    __builtin_amdgcn_global_load_lds(
        (const __attribute__((address_space(1))) void*)g,
        (__attribute__((address_space(3))) void*)l, 16, 0, 0);
}

// ---- Kernel 1: normalize embeddings -> bf16 ----
__global__ void k_embed(const float* __restrict__ emb, unsigned short* __restrict__ ne) {
    int row = blockIdx.x;            // 1024
    int t = threadIdx.x;             // 256, 2 floats each
    float2 v = ((const float2*)(emb + row * EMB))[t];
    float ss = v.x * v.x + v.y * v.y;
    __shared__ float red[4];
    for (int off = 32; off; off >>= 1) ss += __shfl_down(ss, off);
    if ((t & 63) == 0) red[t >> 6] = ss;
    __syncthreads();
    float inv = rsqrtf(red[0] + red[1] + red[2] + red[3]);
    unsigned b0 = f2bf(v.x * inv), b1 = f2bf(v.y * inv);
    ((unsigned*)(ne + row * EMB))[t] = b0 | (b1 << 16);
}

// ---- Kernel 2: normalize weights -> bf16 (one wave per row, padded to 100096) ----
__global__ void k_weight(const float* __restrict__ w, unsigned short* __restrict__ nw) {
    int r = blockIdx.x * 4 + (threadIdx.x >> 6);
    int L = threadIdx.x & 63;
    uint4* dst = (uint4*)(nw + (size_t)r * EMB + L * 8);
    if (r >= NUM_CLASS) { *dst = make_uint4(0, 0, 0, 0); return; }
    const float4* src = (const float4*)(w + (size_t)r * EMB + L * 8);
    float4 a = src[0], b = src[1];
    float ss = a.x*a.x + a.y*a.y + a.z*a.z + a.w*a.w
             + b.x*b.x + b.y*b.y + b.z*b.z + b.w*b.w;
    for (int off = 32; off; off >>= 1) ss += __shfl_down(ss, off);
    ss = __shfl(ss, 0);
    float inv = rsqrtf(ss);
    uint4 o;
    o.x = (unsigned)f2bf(a.x*inv) | ((unsigned)f2bf(a.y*inv) << 16);
    o.y = (unsigned)f2bf(a.z*inv) | ((unsigned)f2bf(a.w*inv) << 16);
    o.z = (unsigned)f2bf(b.x*inv) | ((unsigned)f2bf(b.y*inv) << 16);
    o.w = (unsigned)f2bf(b.z*inv) | ((unsigned)f2bf(b.w*inv) << 16);
    *dst = o;
}

// ---- Kernel 3: target logits from RAW fp32 weights (one wave per row) ----
__global__ void k_tl(const unsigned short* __restrict__ ne, const float* __restrict__ w,
                     const int* __restrict__ labels, float* __restrict__ ftl, float* __restrict__ ftl1) {
    int b = blockIdx.x * 4 + (threadIdx.x >> 6);
    int L = threadIdx.x & 63;
    int lab = labels[b];
    uint4 ua = *(const uint4*)(ne + (size_t)b * EMB + L * 8);
    const float4* wp = (const float4*)(w + (size_t)lab * EMB + L * 8);
    float4 w0 = wp[0], w1 = wp[1];
    float ss = w0.x*w0.x + w0.y*w0.y + w0.z*w0.z + w0.w*w0.w
             + w1.x*w1.x + w1.y*w1.y + w1.z*w1.z + w1.w*w1.w;
    float s = blo(ua.x)*w0.x + bhi(ua.x)*w0.y + blo(ua.y)*w0.z + bhi(ua.y)*w0.w
            + blo(ua.z)*w1.x + bhi(ua.z)*w1.y + blo(ua.w)*w1.z + bhi(ua.w)*w1.w;
    for (int off = 32; off; off >>= 1) {
        s  += __shfl_down(s, off);
        ss += __shfl_down(ss, off);
    }
    if (L == 0) {
        float tl = s * rsqrtf(ss);
        tl = fminf(1.0f, fmaxf(-1.0f, tl));
        float st = sqrtf(fmaxf(0.0f, 1.0f - tl * tl));
        float cos_tm  = tl * COS_M  - st * SIN_M;
        float cos_tm1 = tl * COS_M1 - st * SIN_M1;
        float f  = (tl > THETA_C)  ? cos_tm  : (tl - SINMM);
        float f1 = (tl <= COS_M1)  ? cos_tm1 : (tl + SINMM1);
        ftl[b] = f;
        ftl1[b] = f1;
    }
}

// ---- Kernel 4: 256x256 bf16 MFMA GEMM, 8 waves, 3-buffer counted-vmcnt pipeline ----
// 256^2 tile halves staged global->LDS bytes per output (16 -> 8 B/out): the 128^2
// family was saturating the per-CU vector-memory pipe (~11 B/cy/CU) on re-staging.
// K-granule XOR swizzle (ks ^ ((row>>1)&3)) applied on BOTH sides: inverse-permuted
// global source (load_lds dest stays linear) + same XOR on ds_read -> 2-way banks.
__global__ __launch_bounds__(512, 2)
void k_gemm(const unsigned short* __restrict__ A,   // ne [1024][512]
            const unsigned short* __restrict__ B,   // nw [100096][512]
            const float* __restrict__ ftl, const float* __restrict__ ftl1,
            const int* __restrict__ labels,
            float* __restrict__ out, unsigned* __restrict__ cnt) {
    __shared__ __align__(16) unsigned short ldsA[3 * 8192];   // 48 KB: 3 bufs [256][32]
    __shared__ __align__(16) unsigned short ldsB[3 * 8192];   // 48 KB
    __shared__ float sF[256], sF1[256];
    __shared__ int sLab[256];
    __shared__ unsigned sCnt[16];

    floatx4* ldsE4 = (floatx4*)ldsA;        // epilogue reuse: [32 rows][64 float4] = 32 KB

    const int tid = threadIdx.x;
    // bijective XCD swizzle for nwg=1564 (1564%8=4): q=195,r=4 (m204 formula).
    // Each XCD gets a contiguous wgid run; wgid&3 = row-tile (4 consecutive blocks
    // share one B col-panel -> L2 reuse on-XCD).
    const int flat = blockIdx.x;
    const int xcd = flat & 7, idx = flat >> 3;
    const int wgid = (xcd < 4 ? xcd * 196 : 784 + (xcd - 4) * 195) + idx;
    const int rowBase = (wgid & 3) * BM;       // 0..768
    const int colBase = (wgid >> 2) * BN;      // 0..99840

    if (tid < 256) {
        sF[tid]  = ftl[rowBase + tid];
        sF1[tid] = ftl1[rowBase + tid];
        sLab[tid] = labels[rowBase + tid];
    }

    const int wave = tid >> 6;
    const int lane = tid & 63;
    const int wm = wave >> 2, wn = wave & 3;   // 2M x 4N wave grid; wave owns 128x64

    // staging source pointers, k-granule pre-swizzled (inverse of read XOR)
    const unsigned short* gA[2];
    const unsigned short* gB[2];
    #pragma unroll
    for (int c = 0; c < 2; c++) {
        int gi = c * 512 + tid;                // granule 0..1023 (16B each)
        int row = gi >> 2;                     // 0..255
        int ksrc = (gi & 3) ^ ((row >> 1) & 3);
        gA[c] = A + (size_t)(rowBase + row) * EMB + ksrc * 8;
        gB[c] = B + (size_t)(colBase + row) * EMB + ksrc * 8;
    }

    floatx4 acc[8][4] = {};

#define ISSUE(kkv, b) do {                                              \
        load16(gA[0] + (kkv), &ldsA[(b) * 8192 + tid * 8]);             \
        load16(gA[1] + (kkv), &ldsA[(b) * 8192 + 4096 + tid * 8]);      \
        load16(gB[0] + (kkv), &ldsB[(b) * 8192 + tid * 8]);             \
        load16(gB[1] + (kkv), &ldsB[(b) * 8192 + 4096 + tid * 8]);      \
    } while (0)

    // prologue: 2 K-steps in flight
    ISSUE(0, 0);
    ISSUE(32, 1);

    #pragma unroll
    for (int t = 0; t < NKS; ++t) {
        // counted wait BEFORE barrier (round-7-proven): own tile-t loads landed,
        // t+1's 4 stay in flight; barrier publishes all waves' tile-t loads.
        if (t < NKS - 1) asm volatile("s_waitcnt vmcnt(4)" ::: "memory");
        else             asm volatile("s_waitcnt vmcnt(0)" ::: "memory");
        __builtin_amdgcn_s_barrier();
        if (t + 2 < NKS) ISSUE(t * 32 + 64, (t + 2) % 3);   // prefetch depth 2
        const int buf = t % 3;
        bf16x8 af[8], bf[4];
        #pragma unroll
        for (int mi = 0; mi < 8; mi++) {
            const int r = wm * 128 + mi * 16 + (lane & 15);
            const int ks = lane >> 4;
            af[mi] = *(const bf16x8*)&ldsA[buf * 8192 + r * 32 + ((ks ^ ((r >> 1) & 3)) * 8)];
        }
        #pragma unroll
        for (int ni = 0; ni < 4; ni++) {
            const int r = wn * 64 + ni * 16 + (lane & 15);
            const int ks = lane >> 4;
            bf[ni] = *(const bf16x8*)&ldsB[buf * 8192 + r * 32 + ((ks ^ ((r >> 1) & 3)) * 8)];
        }
        // swapped operands: lane&15 = batch row, (lane>>4)*4 + r = class col
        #pragma unroll
        for (int mi = 0; mi < 8; mi++)
            #pragma unroll
            for (int ni = 0; ni < 4; ni++)
                acc[mi][ni] = __builtin_amdgcn_mfma_f32_16x16x32_bf16(bf[ni], af[mi], acc[mi][ni], 0, 0, 0);
    }
#undef ISSUE
    __syncthreads();   // all K-loop LDS reads done; safe to reuse for epilogue

    // epilogue: per mi (32 rows x 256 cols = 32 KB), math in-reg -> swizzled LDS
    // stage -> write-back with 64 lanes covering one full 1-KB row.
    unsigned cH = 0, cN = 0;
    const int r32 = wm * 16 + (lane & 15);      // LDS row slot 0..31
    #pragma unroll
    for (int mi = 0; mi < 8; mi++) {
        if (mi) __syncthreads();                // protect previous read-back
        const int row = wm * 128 + mi * 16 + (lane & 15);
        const float F = sF[row], F1 = sF1[row];
        const int lab = sLab[row];
        #pragma unroll
        for (int ni = 0; ni < 4; ni++) {
            const int colL = wn * 64 + ni * 16 + (lane >> 4) * 4;
            const int col = colBase + colL;
            const bool valid = col < NUM_CLASS;  // 100000 % 4 == 0
            floatx4 a = acc[mi][ni];
            floatx4 v;
            #pragma unroll
            for (int r = 0; r < 4; r++) {
                float lg = fminf(1.0f, fmaxf(-1.0f, a[r]));
                bool h = lg > F, n = lg > F1;
                cH += (h && valid); cN += (n && valid);
                float val = n ? fmaxf(lg, 1e-30f) : (h ? lg * T_HARD : lg);
                if (col + r == lab) val = F;
                v[r] = val * S_SCALE;
            }
            const int c4 = colL >> 2;            // 0..63
            ldsE4[r32 * 64 + (c4 ^ (r32 & 7))] = v;
        }
        __syncthreads();
        // write-back: 2048 float4s, 4/thread; 64 consecutive lanes = one row (1 KB)
        #pragma unroll
        for (int c = 0; c < 4; c++) {
            const int idx2 = c * 512 + tid;
            const int rr = idx2 >> 6;            // 0..31
            const int c4 = idx2 & 63;
            const int gcol = colBase + c4 * 4;
            if (gcol < NUM_CLASS) {
                const int grow = rowBase + (rr >> 4) * 128 + mi * 16 + (rr & 15);
                floatx4 v = ldsE4[rr * 64 + (c4 ^ (rr & 7))];
                __builtin_nontemporal_store(v, (floatx4*)(out + (size_t)grow * NUM_CLASS + gcol));
            }
        }
    }

    for (int off = 32; off; off >>= 1) { cH += __shfl_down(cH, off); cN += __shfl_down(cN, off); }
    if (lane == 0) { sCnt[wave] = cH; sCnt[8 + wave] = cN; }
    __syncthreads();
    if (tid == 0) {
        unsigned h = 0, n = 0;
        #pragma unroll
        for (int w = 0; w < 8; w++) { h += sCnt[w]; n += sCnt[8 + w]; }
        atomicAdd(&cnt[0], h);
        atomicAdd(&cnt[1], n);
    }
}

// ---- Kernel 5: finalize scalar outputs (separate launch: no fence in k_gemm) ----
__global__ void k_final(const unsigned* __restrict__ cnt, float* __restrict__ o) {
    unsigned hard_cnt = cnt[0], noise_num = cnt[1];
    const unsigned num_all = (unsigned)BATCH * (unsigned)NUM_CLASS;   // 102,400,000
    unsigned easy = num_all - hard_cnt;
    unsigned hard_num = hard_cnt - noise_num;
    float phi = ((float)easy / (float)num_all) * 0.01f;
    o[0] = (float)easy;
    o[1] = (float)noise_num;
    o[2] = (float)hard_num;
    o[3] = phi;
}

extern "C" void kernel_launch(void* const* d_in, const int* in_sizes, int n_in,
                              void* d_out, int out_size, void* d_ws, size_t ws_size,
                              hipStream_t stream) {
    const float* emb = (const float*)d_in[0];
    const float* wgt = (const float*)d_in[1];
    const int* labels = (const int*)d_in[2];
    float* out = (float*)d_out;
    char* ws = (char*)d_ws;

    unsigned* cnt = (unsigned*)ws;                           // 64 B
    float* ftl  = (float*)(ws + 64);                         // 4 KB
    float* ftl1 = (float*)(ws + 8192);                       // 4 KB
    unsigned short* ne = (unsigned short*)(ws + 16384);      // 1 MB
    unsigned short* nw = (unsigned short*)(ws + (1 << 21));  // ~102.5 MB

    hipMemsetAsync(cnt, 0, 64, stream);
    k_embed<<<BATCH, 256, 0, stream>>>(emb, ne);
    k_tl<<<BATCH / 4, 256, 0, stream>>>(ne, wgt, labels, ftl, ftl1);
    k_weight<<<NUM_CLASS_PAD / 4, 256, 0, stream>>>(wgt, nw);
    k_gemm<<<GRID_X, 512, 0, stream>>>(ne, nw, ftl, ftl1, labels, out, cnt);
    k_final<<<1, 1, 0, stream>>>(cnt, out + (size_t)BATCH * NUM_CLASS);
}